// Round 22
// baseline (144.807 us; speedup 1.0000x reference)
//
#include <hip/hip_runtime.h>
#include <math.h>

constexpr int D  = 1024;
constexpr int H  = 16;
constexpr int HD = 64;
constexpr int B  = 2;
constexpr int T  = 2048;
constexpr int M  = B * T;   // 4096

constexpr size_t XSZ = (size_t)M * D;   // 4,194,304
constexpr size_t WSZ = (size_t)D * D;   // 1,048,576

typedef float  f32x4   __attribute__((ext_vector_type(4)));
typedef float  f32x16  __attribute__((ext_vector_type(16)));
typedef __bf16 bf16x8  __attribute__((ext_vector_type(8)));
typedef __bf16 bf16x4  __attribute__((ext_vector_type(4)));
typedef unsigned u32x2 __attribute__((ext_vector_type(2)));
typedef unsigned u32x4 __attribute__((ext_vector_type(4)));

static __device__ inline f32x4 mfma16(bf16x8 a, bf16x8 b, f32x4 c) {
  return __builtin_amdgcn_mfma_f32_16x16x32_bf16(a, b, c, 0, 0, 0);
}
static __device__ inline f32x16 mfma32(bf16x8 a, bf16x8 b, f32x16 c) {
  return __builtin_amdgcn_mfma_f32_32x32x16_bf16(a, b, c, 0, 0, 0);
}
// pack two f32 -> u32 of 2 bf16 (lo = a, hi = b); no builtin on gfx950
static __device__ inline unsigned cvtpk(float a, float b) {
  unsigned r;
  asm("v_cvt_pk_bf16_f32 %0, %1, %2" : "=v"(r) : "v"(a), "v"(b));
  return r;
}
static __device__ inline u32x2 plswap(unsigned a, unsigned b) {
  return __builtin_amdgcn_permlane32_swap(a, b, false, false);
}
// async global->LDS, 16B per lane (dest = wave-uniform base + lane*16)
static __device__ inline void gload16(const __bf16* g, __bf16* l) {
  __builtin_amdgcn_global_load_lds(
      (const __attribute__((address_space(1))) void*)g,
      (__attribute__((address_space(3))) void*)l, 16, 0, 0);
}

// ---------------------------------------------------------------------------
// Fused fp32->bf16 convert of x + 4 weights into contiguous bf16 workspace.
// ---------------------------------------------------------------------------
__global__ __launch_bounds__(256)
void cvt_all(const float* __restrict__ x, const float* __restrict__ wq,
             const float* __restrict__ wk, const float* __restrict__ wv,
             const float* __restrict__ wo, __bf16* __restrict__ out) {
  size_t idx = ((size_t)blockIdx.x * 256 + threadIdx.x) * 8;
  const float* src;
  if      (idx < XSZ)            src = x  + idx;
  else if (idx < XSZ + WSZ)      src = wq + (idx - XSZ);
  else if (idx < XSZ + 2 * WSZ)  src = wk + (idx - XSZ - WSZ);
  else if (idx < XSZ + 3 * WSZ)  src = wv + (idx - XSZ - 2 * WSZ);
  else                           src = wo + (idx - XSZ - 3 * WSZ);
  float4 a = *reinterpret_cast<const float4*>(src);
  float4 b = *reinterpret_cast<const float4*>(src + 4);
  bf16x8 o;
  o[0] = (__bf16)a.x; o[1] = (__bf16)a.y; o[2] = (__bf16)a.z; o[3] = (__bf16)a.w;
  o[4] = (__bf16)b.x; o[5] = (__bf16)b.y; o[6] = (__bf16)b.z; o[7] = (__bf16)b.w;
  *reinterpret_cast<bf16x8*>(out + idx) = o;
}

// ---------------------------------------------------------------------------
// MFMA GEMM. MODE 1: 128x128 tile, fused QKV -> fragment-order Q/K/V.
// MODE 0: 64x128 tile (grid (8,64)=512 blocks = 2/CU), fp32 out.
// Both: BK=64, 256 thr = 4 waves (2x2), global_load_lds staging.
// ---------------------------------------------------------------------------
template<int MODE>
__global__ __launch_bounds__(256)
void gemm_mfma(const __bf16* __restrict__ A,
               const __bf16* __restrict__ W0, const __bf16* __restrict__ W1,
               const __bf16* __restrict__ W2,
               const float* __restrict__ cosT, const float* __restrict__ sinT,
               void* __restrict__ out0, void* __restrict__ out1,
               void* __restrict__ out2) {
  constexpr int BM  = (MODE == 0) ? 64 : 128;   // rows per block
  constexpr int NMT = BM / 32;                  // per-wave m-frags (2 or 4)
  __shared__ __bf16 As[BM * 64];
  __shared__ __bf16 Bs[128 * 64];

  const int tid  = threadIdx.x;
  const int lane = tid & 63;
  const int w    = tid >> 6;     // 0..3
  const int wm   = w >> 1;       // 0..1
  const int wn   = w & 1;        // 0..1 (64 cols each)
  const int l15  = lane & 15, lg = lane >> 4;
  const int m0   = blockIdx.y * BM;

  int which, n0;
  const __bf16* Bw;
  if (MODE == 1) {
    which = blockIdx.x >> 3;
    n0 = (blockIdx.x & 7) * 128;
    Bw = which == 0 ? W0 : which == 1 ? W1 : W2;
  } else {
    which = 0;
    n0 = blockIdx.x * 128;
    Bw = W0;
  }

  f32x4 acc[NMT][4];
  #pragma unroll
  for (int i = 0; i < NMT; ++i)
    #pragma unroll
    for (int j = 0; j < 4; ++j) acc[i][j] = (f32x4){0.f, 0.f, 0.f, 0.f};

  const int r0 = tid >> 3;          // 0..31
  const int c0 = (tid & 7) * 8;     // 0..56

  for (int k0 = 0; k0 < 1024; k0 += 64) {
    #pragma unroll
    for (int i = 0; i < BM / 32; ++i)
      gload16(A + (size_t)(m0 + r0 + 32 * i) * 1024 + k0 + c0,
              As + (tid + 256 * i) * 8);
    #pragma unroll
    for (int i = 0; i < 4; ++i)
      gload16(Bw + (size_t)(n0 + r0 + 32 * i) * 1024 + k0 + c0,
              Bs + (tid + 256 * i) * 8);
    __syncthreads();   // drains vmcnt -> LDS tiles ready

    #pragma unroll
    for (int ks = 0; ks < 2; ++ks) {
      bf16x8 af[NMT], bfr[4];
      #pragma unroll
      for (int mt = 0; mt < NMT; ++mt)
        af[mt] = *reinterpret_cast<const bf16x8*>(
            &As[(wm * (BM / 2) + mt * 16 + l15) * 64 + ks * 32 + lg * 8]);
      #pragma unroll
      for (int nt = 0; nt < 4; ++nt)
        bfr[nt] = *reinterpret_cast<const bf16x8*>(
            &Bs[(wn * 64 + nt * 16 + l15) * 64 + ks * 32 + lg * 8]);
      #pragma unroll
      for (int mt = 0; mt < NMT; ++mt)
        #pragma unroll
        for (int nt = 0; nt < 4; ++nt)
          acc[mt][nt] = mfma16(af[mt], bfr[nt], acc[mt][nt]);
    }
    __syncthreads();
  }

  // Frag: n = n0 + wn*64 + nt*16 + l15 ; m = m0 + wm*(BM/2) + mt*16 + lg*4 + r
  if (MODE == 0) {
    float* o = (float*)out0;
    #pragma unroll
    for (int mt = 0; mt < NMT; ++mt) {
      const int mb = m0 + wm * (BM / 2) + mt * 16 + lg * 4;
      #pragma unroll
      for (int nt = 0; nt < 4; ++nt) {
        const int n = n0 + wn * 64 + nt * 16 + l15;
        #pragma unroll
        for (int r = 0; r < 4; ++r)
          o[(size_t)(mb + r) * 1024 + n] = acc[mt][nt][r];
      }
    }
  } else if (which < 2) {
    // Q or K: RoPE fused; Q scaled by 0.125*log2(e). Fragment-order store:
    //   Q: [bh][t>>5][st][L][e]   K: [bh][t>>6][(t>>5)&1][st][L][e]
    __bf16* dst = which == 0 ? (__bf16*)out0 : (__bf16*)out1;
    const float qs = (which == 0) ? 0.180336880f : 1.0f;
    const int h = (n0 + wn * 64) >> 6;
    const int e  = l15 & 7;
    const int Lh = (l15 >> 3) << 5;
    #pragma unroll
    for (int mt = 0; mt < NMT; ++mt) {
      const int tb   = m0 + wm * (BM / 2) + mt * 16 + lg * 4;
      const int bb   = tb >> 11;
      const int tloc = tb & 2047;
      const int bh   = bb * H + h;
      #pragma unroll
      for (int r = 0; r < 4; ++r) {
        const int t = tloc + r;
        const int L = (t & 31) + Lh;
        size_t fb;
        if (which == 0)
          fb = ((size_t)bh * 64 + (t >> 5)) * 4;
        else
          fb = (((size_t)bh * 32 + (t >> 6)) * 2 + ((t >> 5) & 1)) * 4;
        #pragma unroll
        for (int nt = 0; nt < 2; ++nt) {
          const int hd = nt * 16 + l15;
          const float c = cosT[t * HD + hd];
          const float s = sinT[t * HD + hd];
          const float v1 = acc[mt][nt][r];
          const float v2 = acc[mt][nt + 2][r];
          dst[(fb + nt)     * 512 + L * 8 + e] = (__bf16)((v1 * c - v2 * s) * qs);
          dst[(fb + nt + 2) * 512 + L * 8 + e] = (__bf16)((v2 * c + v1 * s) * qs);
        }
      }
    }
  } else {
    // V: PV-fragment order [bh][t>>6][dg=hd>>5][kc=(t&63)>>4][L][e]
    __bf16* dst = (__bf16*)out2;
    const int h = (n0 + wn * 64) >> 6;
    #pragma unroll
    for (int mt = 0; mt < NMT; ++mt) {
      const int tb   = m0 + wm * (BM / 2) + mt * 16 + lg * 4;
      const int bb   = tb >> 11;
      const int tloc = tb & 2047;
      const int bh   = bb * H + h;
      const int jt   = tloc >> 6;
      const int kt   = tloc & 63;
      const int Lk   = ((kt >> 3) & 1) << 5;
      const int e0   = kt & 7;
      const size_t fb = (((size_t)bh * 32 + jt) * 2) * 4 + (kt >> 4);
      #pragma unroll
      for (int nt = 0; nt < 4; ++nt) {
        const int hd = nt * 16 + l15;
        const int dg = hd >> 5;
        const int L  = (hd & 31) + Lk;
        bf16x4 ov;
        #pragma unroll
        for (int r = 0; r < 4; ++r) ov[r] = (__bf16)acc[mt][nt][r];
        *reinterpret_cast<bf16x4*>(
            &dst[(fb + (size_t)dg * 4) * 512 + L * 8 + e0]) = ov;
      }
    }
  }
}

// ---------------------------------------------------------------------------
// attn_v18: v17 with the V-pipeline index bug fixed.
// v17's phase-A V-issue computed `jn = (j+1<NT)? j+1 : NT-1; LOADV8(jn)`,
// which loads V(j+1) while phase B consumes V(j) -> wrong V on odd tiles
// (absmax 0.157). Fix: LOADV8(j) — V for the NEW current tile.
// Also: drain vmcnt(0) after the loop (outstanding clamped prefetches write
// kA/kB registers the allocator may reuse for epilogue temps).
// vmcnt ledger (steady state): before LOADK8 in-flight {K(j+2-ish), V(j)}=16
// -> LOADK8 ->24 -> WAITN(8) leaves only newest K prefetch.
// ---------------------------------------------------------------------------
#define GLDO(dst, ptr, OFF)                                                   \
  asm volatile("global_load_dwordx4 %0, %1, off offset:" #OFF                 \
               : "=&v"(dst) : "v"(ptr) : "memory")
#define WAITN(N)                                                              \
  do {                                                                        \
    asm volatile("s_waitcnt vmcnt(" #N ")" ::: "memory");                     \
    __builtin_amdgcn_sched_barrier(0);                                        \
  } while (0)

__global__ __launch_bounds__(256, 2)
void attn_v18(const __bf16* __restrict__ Qf, const __bf16* __restrict__ Kf,
              const __bf16* __restrict__ Vf, __bf16* __restrict__ Ob) {
  const int tid  = threadIdx.x;
  const int lane = tid & 63;
  const int w    = tid >> 6;          // 0..3
  const int l31  = lane & 31;
  const int hi   = lane >> 5;         // 0..1
  const int bx   = blockIdx.x;        // 0..15
  const int by   = blockIdx.y;        // 0..31
  const int bh   = (bx & 7) + 8 * (by >> 3);   // XCD = bh&7
  const int x    = (bx >> 3) + 2 * (by & 7);   // 0..15

  const int wi = (bh < 16) ? w : (w ^ 1);
  const int qt = (wi == 0) ? 2 * x : (wi == 1) ? 63 - 2 * x
               : (wi == 2) ? 2 * x + 1 : 62 - 2 * x;
  const int q0w = qt * 32;
  const int NT  = (qt >> 1) + 1;      // 64-key tiles

  const __bf16* qbase = Qf + (((size_t)bh * 64 + qt) * 4) * 512 + lane * 8;
  bf16x8 qfr[4];
  #pragma unroll
  for (int st = 0; st < 4; ++st)
    qfr[st] = *reinterpret_cast<const bf16x8*>(qbase + st * 512);

  f32x16 zv;
  #pragma unroll
  for (int i = 0; i < 16; ++i) zv[i] = 0.f;

  float m_run = -INFINITY, l_run = 0.f;
  f32x16 oacc0, oacc1;
  #pragma unroll
  for (int i = 0; i < 16; ++i) { oacc0[i] = 0.f; oacc1[i] = 0.f; }

  const __bf16* kbase = Kf + ((size_t)bh * 32 * 8) * 512 + lane * 8;
  const __bf16* vbase = Vf + ((size_t)bh * 32 * 8) * 512 + lane * 8;

// 8 frags/tile: elems 0,512,..,3584 = bytes 0..7168; two bases (+4096B).
#define LOADK8(K0, K1, K2, K3, K4, K5, K6, K7, jj)                            \
  do {                                                                        \
    const __bf16* _p0 = kbase + (size_t)(jj) * 4096;                          \
    const __bf16* _p1 = _p0 + 2048;                                           \
    GLDO(K0, _p0, 0);    GLDO(K1, _p0, 1024);                                 \
    GLDO(K2, _p0, 2048); GLDO(K3, _p0, 3072);                                 \
    GLDO(K4, _p1, 0);    GLDO(K5, _p1, 1024);                                 \
    GLDO(K6, _p1, 2048); GLDO(K7, _p1, 3072);                                 \
  } while (0)

#define LOADV8(jj)                                                            \
  do {                                                                        \
    const __bf16* _p0 = vbase + (size_t)(jj) * 4096;                          \
    const __bf16* _p1 = _p0 + 2048;                                           \
    GLDO(VV0, _p0, 0);    GLDO(VV1, _p0, 1024);                               \
    GLDO(VV2, _p0, 2048); GLDO(VV3, _p0, 3072);                               \
    GLDO(VV4, _p1, 0);    GLDO(VV5, _p1, 1024);                               \
    GLDO(VV6, _p1, 2048); GLDO(VV7, _p1, 3072);                               \
  } while (0)

#define QK64(K0, K1, K2, K3, K4, K5, K6, K7)                                  \
  do {                                                                        \
    sv0 = mfma32(K0, qfr[0], zv);                                             \
    sv0 = mfma32(K1, qfr[1], sv0);                                            \
    sv0 = mfma32(K2, qfr[2], sv0);                                            \
    sv0 = mfma32(K3, qfr[3], sv0);                                            \
    sv1 = mfma32(K4, qfr[0], zv);                                             \
    sv1 = mfma32(K5, qfr[1], sv1);                                            \
    sv1 = mfma32(K6, qfr[2], sv1);                                            \
    sv1 = mfma32(K7, qfr[3], sv1);                                            \
  } while (0)

#define SMPV(jj)                                                              \
  do {                                                                        \
    if ((jj) == NT - 1) { /* diagonal: causal mask */                         \
      const int _q  = q0w + l31;                                              \
      const int _k0 = (jj) * 64 + 4 * hi;                                     \
      _Pragma("unroll")                                                       \
      for (int _r = 0; _r < 16; ++_r) {                                       \
        const int _key = _k0 + (_r & 3) + 8 * (_r >> 2);                      \
        if (_key > _q)      sv0[_r] = -INFINITY;                              \
        if (_key + 32 > _q) sv1[_r] = -INFINITY;                              \
      }                                                                       \
    }                                                                         \
    float _mx[16];                                                            \
    _Pragma("unroll")                                                         \
    for (int _i = 0; _i < 16; ++_i) _mx[_i] = fmaxf(sv0[_i], sv1[_i]);        \
    _Pragma("unroll")                                                         \
    for (int _s = 8; _s > 0; _s >>= 1)                                        \
      _Pragma("unroll")                                                       \
      for (int _i = 0; _i < 8; ++_i)                                          \
        if (_i < _s) _mx[_i] = fmaxf(_mx[_i], _mx[_i + _s]);                  \
    union { float f; unsigned u; } _cv; _cv.f = _mx[0];                       \
    u32x2 _sw = plswap(_cv.u, _cv.u);                                         \
    union { unsigned u; float f; } _c0, _c1; _c0.u = _sw[0]; _c1.u = _sw[1];  \
    const float _pmax = fmaxf(_c0.f, _c1.f);                                  \
    if (__any(_pmax > m_run + 8.f)) {                                         \
      const float _mn = fmaxf(m_run, _pmax);                                  \
      const float _rs = exp2f(m_run - _mn);                                   \
      l_run *= _rs;                                                           \
      _Pragma("unroll")                                                       \
      for (int _i = 0; _i < 16; ++_i) { oacc0[_i] *= _rs; oacc1[_i] *= _rs; } \
      m_run = _mn;                                                            \
    }                                                                         \
    _Pragma("unroll")                                                         \
    for (int _i = 0; _i < 16; ++_i) {                                         \
      sv0[_i] = exp2f(sv0[_i] - m_run);                                       \
      sv1[_i] = exp2f(sv1[_i] - m_run);                                       \
    }                                                                         \
    float _sm[16];                                                            \
    _Pragma("unroll")                                                         \
    for (int _i = 0; _i < 16; ++_i) _sm[_i] = sv0[_i] + sv1[_i];              \
    _Pragma("unroll")                                                         \
    for (int _s = 8; _s > 0; _s >>= 1)                                        \
      _Pragma("unroll")                                                       \
      for (int _i = 0; _i < 8; ++_i)                                          \
        if (_i < _s) _sm[_i] += _sm[_i + _s];                                 \
    l_run += _sm[0];                                                          \
    unsigned _cp0[8], _cp1[8];                                                \
    _Pragma("unroll")                                                         \
    for (int _m = 0; _m < 4; ++_m) {                                          \
      _cp0[2 * _m]     = cvtpk(sv0[4 * _m],     sv0[4 * _m + 1]);             \
      _cp0[2 * _m + 1] = cvtpk(sv0[4 * _m + 2], sv0[4 * _m + 3]);             \
      _cp1[2 * _m]     = cvtpk(sv1[4 * _m],     sv1[4 * _m + 1]);             \
      _cp1[2 * _m + 1] = cvtpk(sv1[4 * _m + 2], sv1[4 * _m + 3]);             \
    }                                                                         \
    {                                                                         \
      u32x2 _r0 = plswap(_cp0[0], _cp0[2]);                                   \
      u32x2 _r1 = plswap(_cp0[1], _cp0[3]);                                   \
      union { u32x4 u; bf16x8 v; } _pu;                                       \
      _pu.u = (u32x4){_r0[0], _r1[0], _r0[1], _r1[1]};                        \
      oacc0 = mfma32(VV0, _pu.v, oacc0);                                      \
      oacc1 = mfma32(VV4, _pu.v, oacc1);                                      \
    }                                                                         \
    {                                                                         \
      u32x2 _r0 = plswap(_cp0[4], _cp0[6]);                                   \
      u32x2 _r1 = plswap(_cp0[5], _cp0[7]);                                   \
      union { u32x4 u; bf16x8 v; } _pu;                                       \
      _pu.u = (u32x4){_r0[0], _r1[0], _r0[1], _r1[1]};                        \
      oacc0 = mfma32(VV1, _pu.v, oacc0);                                      \
      oacc1 = mfma32(VV5, _pu.v, oacc1);                                      \
    }                                                                         \
    {                                                                         \
      u32x2 _r0 = plswap(_cp1[0], _cp1[2]);                                   \
      u32x2 _r1 = plswap(_cp1[1], _cp1[3]);                                   \
      union { u32x4 u; bf16x8 v; } _pu;                                       \
      _pu.u = (u32x4){_r0[0], _r1[0], _r0[1], _r1[1]};                        \
      oacc0 = mfma32(VV2, _pu.v, oacc0);                                      \
      oacc1 = mfma32(VV6, _pu.v, oacc1);                                      \
    }                                                                         \
    {                                                                         \
      u32x2 _r0 = plswap(_cp1[4], _cp1[6]);                                   \
      u32x2 _r1 = plswap(_cp1[5], _cp1[7]);                                   \
      union { u32x4 u; bf16x8 v; } _pu;                                       \
      _pu.u = (u32x4){_r0[0], _r1[0], _r0[1], _r1[1]};                        \
      oacc0 = mfma32(VV3, _pu.v, oacc0);                                      \
      oacc1 = mfma32(VV7, _pu.v, oacc1);                                      \
    }                                                                         \
  } while (0)

  bf16x8 kA0, kA1, kA2, kA3, kA4, kA5, kA6, kA7;
  bf16x8 kB0, kB1, kB2, kB3, kB4, kB5, kB6, kB7;
  bf16x8 VV0, VV1, VV2, VV3, VV4, VV5, VV6, VV7;
  f32x16 sv0, sv1;

  // Prologue: K(0)->kA, K(1)->kB, V(0); wait so only {K(1),V(0)} in flight.
  LOADK8(kA0, kA1, kA2, kA3, kA4, kA5, kA6, kA7, 0);
  {
    const int j1 = (1 < NT) ? 1 : 0;
    LOADK8(kB0, kB1, kB2, kB3, kB4, kB5, kB6, kB7, j1);
  }
  LOADV8(0);
  WAITN(16);   // K(0) complete

  int j = 0;
  #pragma unroll 1
  for (;;) {
    // phase A: K(j) in kA (complete), V(j) in VV (in flight)
    QK64(kA0, kA1, kA2, kA3, kA4, kA5, kA6, kA7);
    {
      const int jn = (j + 2 < NT) ? j + 2 : NT - 1;
      LOADK8(kA0, kA1, kA2, kA3, kA4, kA5, kA6, kA7, jn);
    }
    WAITN(8);    // V(j) + K(j+1) complete; newest K prefetch in flight
    SMPV(j);
    if (++j >= NT) break;
    LOADV8(j);   // V for the NEW current tile (v17 bug: loaded j+1)

    // phase B: K(j) in kB (complete), V(j) in VV (in flight)
    QK64(kB0, kB1, kB2, kB3, kB4, kB5, kB6, kB7);
    {
      const int jn = (j + 2 < NT) ? j + 2 : NT - 1;
      LOADK8(kB0, kB1, kB2, kB3, kB4, kB5, kB6, kB7, jn);
    }
    WAITN(8);
    SMPV(j);
    if (++j >= NT) break;
    LOADV8(j);
  }
  // Drain outstanding prefetches: they write kA/kB/VV registers the
  // allocator may reuse for epilogue temps.
  asm volatile("s_waitcnt vmcnt(0)" ::: "memory");
  __builtin_amdgcn_sched_barrier(0);
#undef SMPV
#undef QK64
#undef LOADV8
#undef LOADK8

  // ---- epilogue: O rows hd = (reg&3)+8*(reg>>2)+4hi, q col = l31 ----
  const float l_tot = l_run + __shfl_xor(l_run, 32);
  const float inv = 1.f / l_tot;
  const int b = bh >> 4, h = bh & 15;
  const int q_abs = q0w + l31;
  const size_t rowbase = ((size_t)(b * T + q_abs)) * 1024 + h * 64;
  #pragma unroll
  for (int rg = 0; rg < 4; ++rg) {
    bf16x4 o0, o1;
    #pragma unroll
    for (int r = 0; r < 4; ++r) {
      o0[r] = (__bf16)(oacc0[rg * 4 + r] * inv);
      o1[r] = (__bf16)(oacc1[rg * 4 + r] * inv);
    }
    *reinterpret_cast<bf16x4*>(&Ob[rowbase + rg * 8 + hi * 4])      = o0;
    *reinterpret_cast<bf16x4*>(&Ob[rowbase + 32 + rg * 8 + hi * 4]) = o1;
  }
}

// ---------------------------------------------------------------------------
extern "C" void kernel_launch(void* const* d_in, const int* in_sizes, int n_in,
                              void* d_out, int out_size, void* d_ws, size_t ws_size,
                              hipStream_t stream) {
  const float* x    = (const float*)d_in[0];
  const float* cosT = (const float*)d_in[1];
  const float* sinT = (const float*)d_in[2];
  // d_in[3] = mask (causal, analytic)
  const float* wq   = (const float*)d_in[4];
  const float* wk   = (const float*)d_in[5];
  const float* wv   = (const float*)d_in[6];
  const float* wo   = (const float*)d_in[7];
  float* out = (float*)d_out;

  __bf16* xb   = (__bf16*)d_ws;
  __bf16* wqb  = xb  + XSZ;
  __bf16* wkb  = wqb + WSZ;
  __bf16* wvb  = wkb + WSZ;
  __bf16* wob  = wvb + WSZ;
  __bf16* Qfb  = wob + WSZ;      // fragment-order Q (pre-scaled)
  __bf16* Kfb  = Qfb + XSZ;      // fragment-order K
  __bf16* Vfb  = Kfb + XSZ;      // fragment-order V
  __bf16* attb = Vfb + XSZ;      // [M][1024]

  cvt_all<<<(XSZ + 4 * WSZ) / 8 / 256, 256, 0, stream>>>(x, wq, wk, wv, wo, xb);

  gemm_mfma<1><<<dim3(24, 32), 256, 0, stream>>>(
      xb, wqb, wkb, wvb, cosT, sinT, Qfb, Kfb, Vfb);

  attn_v18<<<dim3(16, 32), 256, 0, stream>>>(Qfb, Kfb, Vfb, attb);

  gemm_mfma<0><<<dim3(8, 64), 256, 0, stream>>>(
      attb, wob, nullptr, nullptr, nullptr, nullptr, out, nullptr, nullptr);
}

// Round 23
// 141.277 us; speedup vs baseline: 1.0250x; 1.0250x over previous
//
#include <hip/hip_runtime.h>
#include <math.h>

constexpr int D  = 1024;
constexpr int H  = 16;
constexpr int HD = 64;
constexpr int B  = 2;
constexpr int T  = 2048;
constexpr int M  = B * T;   // 4096

constexpr size_t XSZ = (size_t)M * D;   // 4,194,304
constexpr size_t WSZ = (size_t)D * D;   // 1,048,576

typedef float  f32x4   __attribute__((ext_vector_type(4)));
typedef float  f32x16  __attribute__((ext_vector_type(16)));
typedef __bf16 bf16x8  __attribute__((ext_vector_type(8)));
typedef __bf16 bf16x4  __attribute__((ext_vector_type(4)));
typedef unsigned u32x2 __attribute__((ext_vector_type(2)));
typedef unsigned u32x4 __attribute__((ext_vector_type(4)));

static __device__ inline f32x4 mfma16(bf16x8 a, bf16x8 b, f32x4 c) {
  return __builtin_amdgcn_mfma_f32_16x16x32_bf16(a, b, c, 0, 0, 0);
}
static __device__ inline f32x16 mfma32(bf16x8 a, bf16x8 b, f32x16 c) {
  return __builtin_amdgcn_mfma_f32_32x32x16_bf16(a, b, c, 0, 0, 0);
}
// pack two f32 -> u32 of 2 bf16 (lo = a, hi = b); no builtin on gfx950
static __device__ inline unsigned cvtpk(float a, float b) {
  unsigned r;
  asm("v_cvt_pk_bf16_f32 %0, %1, %2" : "=v"(r) : "v"(a), "v"(b));
  return r;
}
static __device__ inline u32x2 plswap(unsigned a, unsigned b) {
  return __builtin_amdgcn_permlane32_swap(a, b, false, false);
}
// async global->LDS, 16B per lane (dest = wave-uniform base + lane*16)
static __device__ inline void gload16(const __bf16* g, __bf16* l) {
  __builtin_amdgcn_global_load_lds(
      (const __attribute__((address_space(1))) void*)g,
      (__attribute__((address_space(3))) void*)l, 16, 0, 0);
}

// ---------------------------------------------------------------------------
// Fused fp32->bf16 convert of x + 4 weights into contiguous bf16 workspace.
// ---------------------------------------------------------------------------
__global__ __launch_bounds__(256)
void cvt_all(const float* __restrict__ x, const float* __restrict__ wq,
             const float* __restrict__ wk, const float* __restrict__ wv,
             const float* __restrict__ wo, __bf16* __restrict__ out) {
  size_t idx = ((size_t)blockIdx.x * 256 + threadIdx.x) * 8;
  const float* src;
  if      (idx < XSZ)            src = x  + idx;
  else if (idx < XSZ + WSZ)      src = wq + (idx - XSZ);
  else if (idx < XSZ + 2 * WSZ)  src = wk + (idx - XSZ - WSZ);
  else if (idx < XSZ + 3 * WSZ)  src = wv + (idx - XSZ - 2 * WSZ);
  else                           src = wo + (idx - XSZ - 3 * WSZ);
  float4 a = *reinterpret_cast<const float4*>(src);
  float4 b = *reinterpret_cast<const float4*>(src + 4);
  bf16x8 o;
  o[0] = (__bf16)a.x; o[1] = (__bf16)a.y; o[2] = (__bf16)a.z; o[3] = (__bf16)a.w;
  o[4] = (__bf16)b.x; o[5] = (__bf16)b.y; o[6] = (__bf16)b.z; o[7] = (__bf16)b.w;
  *reinterpret_cast<bf16x8*>(out + idx) = o;
}

// ---------------------------------------------------------------------------
// MFMA GEMM. MODE 1: 128x128 tile, fused QKV -> fragment-order Q/K/V.
// MODE 0: 64x128 tile (grid (8,64)=512 blocks = 2/CU), fp32 out.
// Both: BK=64, 256 thr = 4 waves (2x2), global_load_lds staging.
// ---------------------------------------------------------------------------
template<int MODE>
__global__ __launch_bounds__(256)
void gemm_mfma(const __bf16* __restrict__ A,
               const __bf16* __restrict__ W0, const __bf16* __restrict__ W1,
               const __bf16* __restrict__ W2,
               const float* __restrict__ cosT, const float* __restrict__ sinT,
               void* __restrict__ out0, void* __restrict__ out1,
               void* __restrict__ out2) {
  constexpr int BM  = (MODE == 0) ? 64 : 128;   // rows per block
  constexpr int NMT = BM / 32;                  // per-wave m-frags (2 or 4)
  __shared__ __bf16 As[BM * 64];
  __shared__ __bf16 Bs[128 * 64];

  const int tid  = threadIdx.x;
  const int lane = tid & 63;
  const int w    = tid >> 6;     // 0..3
  const int wm   = w >> 1;       // 0..1
  const int wn   = w & 1;        // 0..1 (64 cols each)
  const int l15  = lane & 15, lg = lane >> 4;
  const int m0   = blockIdx.y * BM;

  int which, n0;
  const __bf16* Bw;
  if (MODE == 1) {
    which = blockIdx.x >> 3;
    n0 = (blockIdx.x & 7) * 128;
    Bw = which == 0 ? W0 : which == 1 ? W1 : W2;
  } else {
    which = 0;
    n0 = blockIdx.x * 128;
    Bw = W0;
  }

  f32x4 acc[NMT][4];
  #pragma unroll
  for (int i = 0; i < NMT; ++i)
    #pragma unroll
    for (int j = 0; j < 4; ++j) acc[i][j] = (f32x4){0.f, 0.f, 0.f, 0.f};

  const int r0 = tid >> 3;          // 0..31
  const int c0 = (tid & 7) * 8;     // 0..56

  for (int k0 = 0; k0 < 1024; k0 += 64) {
    #pragma unroll
    for (int i = 0; i < BM / 32; ++i)
      gload16(A + (size_t)(m0 + r0 + 32 * i) * 1024 + k0 + c0,
              As + (tid + 256 * i) * 8);
    #pragma unroll
    for (int i = 0; i < 4; ++i)
      gload16(Bw + (size_t)(n0 + r0 + 32 * i) * 1024 + k0 + c0,
              Bs + (tid + 256 * i) * 8);
    __syncthreads();   // drains vmcnt -> LDS tiles ready

    #pragma unroll
    for (int ks = 0; ks < 2; ++ks) {
      bf16x8 af[NMT], bfr[4];
      #pragma unroll
      for (int mt = 0; mt < NMT; ++mt)
        af[mt] = *reinterpret_cast<const bf16x8*>(
            &As[(wm * (BM / 2) + mt * 16 + l15) * 64 + ks * 32 + lg * 8]);
      #pragma unroll
      for (int nt = 0; nt < 4; ++nt)
        bfr[nt] = *reinterpret_cast<const bf16x8*>(
            &Bs[(wn * 64 + nt * 16 + l15) * 64 + ks * 32 + lg * 8]);
      #pragma unroll
      for (int mt = 0; mt < NMT; ++mt)
        #pragma unroll
        for (int nt = 0; nt < 4; ++nt)
          acc[mt][nt] = mfma16(af[mt], bfr[nt], acc[mt][nt]);
    }
    __syncthreads();
  }

  // Frag: n = n0 + wn*64 + nt*16 + l15 ; m = m0 + wm*(BM/2) + mt*16 + lg*4 + r
  if (MODE == 0) {
    float* o = (float*)out0;
    #pragma unroll
    for (int mt = 0; mt < NMT; ++mt) {
      const int mb = m0 + wm * (BM / 2) + mt * 16 + lg * 4;
      #pragma unroll
      for (int nt = 0; nt < 4; ++nt) {
        const int n = n0 + wn * 64 + nt * 16 + l15;
        #pragma unroll
        for (int r = 0; r < 4; ++r)
          o[(size_t)(mb + r) * 1024 + n] = acc[mt][nt][r];
      }
    }
  } else if (which < 2) {
    // Q or K: RoPE fused; Q scaled by 0.125*log2(e). Fragment-order store:
    //   Q: [bh][t>>5][st][L][e]   K: [bh][t>>6][(t>>5)&1][st][L][e]
    __bf16* dst = which == 0 ? (__bf16*)out0 : (__bf16*)out1;
    const float qs = (which == 0) ? 0.180336880f : 1.0f;
    const int h = (n0 + wn * 64) >> 6;
    const int e  = l15 & 7;
    const int Lh = (l15 >> 3) << 5;
    #pragma unroll
    for (int mt = 0; mt < NMT; ++mt) {
      const int tb   = m0 + wm * (BM / 2) + mt * 16 + lg * 4;
      const int bb   = tb >> 11;
      const int tloc = tb & 2047;
      const int bh   = bb * H + h;
      #pragma unroll
      for (int r = 0; r < 4; ++r) {
        const int t = tloc + r;
        const int L = (t & 31) + Lh;
        size_t fb;
        if (which == 0)
          fb = ((size_t)bh * 64 + (t >> 5)) * 4;
        else
          fb = (((size_t)bh * 32 + (t >> 6)) * 2 + ((t >> 5) & 1)) * 4;
        #pragma unroll
        for (int nt = 0; nt < 2; ++nt) {
          const int hd = nt * 16 + l15;
          const float c = cosT[t * HD + hd];
          const float s = sinT[t * HD + hd];
          const float v1 = acc[mt][nt][r];
          const float v2 = acc[mt][nt + 2][r];
          dst[(fb + nt)     * 512 + L * 8 + e] = (__bf16)((v1 * c - v2 * s) * qs);
          dst[(fb + nt + 2) * 512 + L * 8 + e] = (__bf16)((v2 * c + v1 * s) * qs);
        }
      }
    }
  } else {
    // V: PV-fragment order [bh][t>>6][dg=hd>>5][kc=(t&63)>>4][L][e]
    __bf16* dst = (__bf16*)out2;
    const int h = (n0 + wn * 64) >> 6;
    #pragma unroll
    for (int mt = 0; mt < NMT; ++mt) {
      const int tb   = m0 + wm * (BM / 2) + mt * 16 + lg * 4;
      const int bb   = tb >> 11;
      const int tloc = tb & 2047;
      const int bh   = bb * H + h;
      const int jt   = tloc >> 6;
      const int kt   = tloc & 63;
      const int Lk   = ((kt >> 3) & 1) << 5;
      const int e0   = kt & 7;
      const size_t fb = (((size_t)bh * 32 + jt) * 2) * 4 + (kt >> 4);
      #pragma unroll
      for (int nt = 0; nt < 4; ++nt) {
        const int hd = nt * 16 + l15;
        const int dg = hd >> 5;
        const int L  = (hd & 31) + Lk;
        bf16x4 ov;
        #pragma unroll
        for (int r = 0; r < 4; ++r) ov[r] = (__bf16)acc[mt][nt][r];
        *reinterpret_cast<bf16x4*>(
            &dst[(fb + (size_t)dg * 4) * 512 + L * 8 + e0]) = ov;
      }
    }
  }
}

// ---------------------------------------------------------------------------
// attn_v15 (best measured: 62.4 µs; total 141.3 µs in round 18).
// 2-tile software pipeline: QK(j+1) || softmax(j) || PV(j); fragment-order
// Q/K/V (coalesced 1KB operand loads); in-register softmax via
// cvt_pk+permlane32_swap; defer-max (THR=8, log2 domain, scale pre-folded);
// no LDS, no barriers; XCD = bh&7 locality; per-SIMD complementary balance.
// ---------------------------------------------------------------------------
__global__ __launch_bounds__(256, 2)
void attn_v15(const __bf16* __restrict__ Qf, const __bf16* __restrict__ Kf,
              const __bf16* __restrict__ Vf, __bf16* __restrict__ Ob) {
  const int tid  = threadIdx.x;
  const int lane = tid & 63;
  const int w    = tid >> 6;          // 0..3
  const int l31  = lane & 31;
  const int hi   = lane >> 5;         // 0..1
  const int bx   = blockIdx.x;        // 0..15
  const int by   = blockIdx.y;        // 0..31
  const int bh   = (bx & 7) + 8 * (by >> 3);   // XCD = bh&7
  const int x    = (bx >> 3) + 2 * (by & 7);   // 0..15

  const int wi = (bh < 16) ? w : (w ^ 1);
  const int qt = (wi == 0) ? 2 * x : (wi == 1) ? 63 - 2 * x
               : (wi == 2) ? 2 * x + 1 : 62 - 2 * x;
  const int q0w = qt * 32;
  const int NT  = (qt >> 1) + 1;      // 64-key tiles

  const __bf16* qbase = Qf + (((size_t)bh * 64 + qt) * 4) * 512 + lane * 8;
  bf16x8 qfr[4];
  #pragma unroll
  for (int st = 0; st < 4; ++st)
    qfr[st] = *reinterpret_cast<const bf16x8*>(qbase + st * 512);

  f32x16 zv;
  #pragma unroll
  for (int i = 0; i < 16; ++i) zv[i] = 0.f;

  float m_run = -INFINITY, l_run = 0.f;
  f32x16 oacc0, oacc1;
  #pragma unroll
  for (int i = 0; i < 16; ++i) { oacc0[i] = 0.f; oacc1[i] = 0.f; }

  const __bf16* kbase = Kf + ((size_t)bh * 32 * 8) * 512 + lane * 8;
  const __bf16* vbase = Vf + ((size_t)bh * 32 * 8) * 512 + lane * 8;

#define LOADK8(K0, K1, K2, K3, K4, K5, K6, K7, jj)                            \
  do {                                                                        \
    const __bf16* _kp = kbase + (size_t)(jj) * 8 * 512;                       \
    K0 = *reinterpret_cast<const bf16x8*>(_kp);                               \
    K1 = *reinterpret_cast<const bf16x8*>(_kp + 512);                         \
    K2 = *reinterpret_cast<const bf16x8*>(_kp + 1024);                        \
    K3 = *reinterpret_cast<const bf16x8*>(_kp + 1536);                        \
    K4 = *reinterpret_cast<const bf16x8*>(_kp + 2048);                        \
    K5 = *reinterpret_cast<const bf16x8*>(_kp + 2560);                        \
    K6 = *reinterpret_cast<const bf16x8*>(_kp + 3072);                        \
    K7 = *reinterpret_cast<const bf16x8*>(_kp + 3584);                        \
    __builtin_amdgcn_sched_barrier(0);                                        \
  } while (0)

#define LOADV8(jj)                                                            \
  do {                                                                        \
    const __bf16* _vp = vbase + (size_t)(jj) * 8 * 512;                       \
    VV0 = *reinterpret_cast<const bf16x8*>(_vp);                              \
    VV1 = *reinterpret_cast<const bf16x8*>(_vp + 512);                        \
    VV2 = *reinterpret_cast<const bf16x8*>(_vp + 1024);                       \
    VV3 = *reinterpret_cast<const bf16x8*>(_vp + 1536);                       \
    VV4 = *reinterpret_cast<const bf16x8*>(_vp + 2048);                       \
    VV5 = *reinterpret_cast<const bf16x8*>(_vp + 2560);                       \
    VV6 = *reinterpret_cast<const bf16x8*>(_vp + 3072);                       \
    VV7 = *reinterpret_cast<const bf16x8*>(_vp + 3584);                       \
    __builtin_amdgcn_sched_barrier(0);                                        \
  } while (0)

// QK: two 4-deep MFMA chains; results land in SV0/SV1 (consumed NEXT phase)
#define QK64(SV0, SV1, K0, K1, K2, K3, K4, K5, K6, K7)                        \
  do {                                                                        \
    SV0 = mfma32(K0, qfr[0], zv);                                             \
    SV0 = mfma32(K1, qfr[1], SV0);                                            \
    SV0 = mfma32(K2, qfr[2], SV0);                                            \
    SV0 = mfma32(K3, qfr[3], SV0);                                            \
    SV1 = mfma32(K4, qfr[0], zv);                                             \
    SV1 = mfma32(K5, qfr[1], SV1);                                            \
    SV1 = mfma32(K6, qfr[2], SV1);                                            \
    SV1 = mfma32(K7, qfr[3], SV1);                                            \
  } while (0)

#define SMPV(SV0, SV1, jj)                                                    \
  do {                                                                        \
    if ((jj) == NT - 1) {                                                     \
      const int _q  = q0w + l31;                                              \
      const int _k0 = (jj) * 64 + 4 * hi;                                     \
      _Pragma("unroll")                                                       \
      for (int _r = 0; _r < 16; ++_r) {                                       \
        const int _key = _k0 + (_r & 3) + 8 * (_r >> 2);                      \
        if (_key > _q)      SV0[_r] = -INFINITY;                              \
        if (_key + 32 > _q) SV1[_r] = -INFINITY;                              \
      }                                                                       \
    }                                                                         \
    float _mx[16];                                                            \
    _Pragma("unroll")                                                         \
    for (int _i = 0; _i < 16; ++_i) _mx[_i] = fmaxf(SV0[_i], SV1[_i]);        \
    _Pragma("unroll")                                                         \
    for (int _s = 8; _s > 0; _s >>= 1)                                        \
      _Pragma("unroll")                                                       \
      for (int _i = 0; _i < 8; ++_i)                                          \
        if (_i < _s) _mx[_i] = fmaxf(_mx[_i], _mx[_i + _s]);                  \
    union { float f; unsigned u; } _cv; _cv.f = _mx[0];                       \
    u32x2 _sw = plswap(_cv.u, _cv.u);                                         \
    union { unsigned u; float f; } _c0, _c1; _c0.u = _sw[0]; _c1.u = _sw[1];  \
    const float _pmax = fmaxf(_c0.f, _c1.f);                                  \
    if (__any(_pmax > m_run + 8.f)) {                                         \
      const float _mn = fmaxf(m_run, _pmax);                                  \
      const float _rs = exp2f(m_run - _mn);                                   \
      l_run *= _rs;                                                           \
      _Pragma("unroll")                                                       \
      for (int _i = 0; _i < 16; ++_i) { oacc0[_i] *= _rs; oacc1[_i] *= _rs; } \
      m_run = _mn;                                                            \
    }                                                                         \
    _Pragma("unroll")                                                         \
    for (int _i = 0; _i < 16; ++_i) {                                         \
      SV0[_i] = exp2f(SV0[_i] - m_run);                                       \
      SV1[_i] = exp2f(SV1[_i] - m_run);                                       \
    }                                                                         \
    float _sm[16];                                                            \
    _Pragma("unroll")                                                         \
    for (int _i = 0; _i < 16; ++_i) _sm[_i] = SV0[_i] + SV1[_i];              \
    _Pragma("unroll")                                                         \
    for (int _s = 8; _s > 0; _s >>= 1)                                        \
      _Pragma("unroll")                                                       \
      for (int _i = 0; _i < 8; ++_i)                                          \
        if (_i < _s) _sm[_i] += _sm[_i + _s];                                 \
    l_run += _sm[0];                                                          \
    unsigned _cp0[8], _cp1[8];                                                \
    _Pragma("unroll")                                                         \
    for (int _m = 0; _m < 4; ++_m) {                                          \
      _cp0[2 * _m]     = cvtpk(SV0[4 * _m],     SV0[4 * _m + 1]);             \
      _cp0[2 * _m + 1] = cvtpk(SV0[4 * _m + 2], SV0[4 * _m + 3]);             \
      _cp1[2 * _m]     = cvtpk(SV1[4 * _m],     SV1[4 * _m + 1]);             \
      _cp1[2 * _m + 1] = cvtpk(SV1[4 * _m + 2], SV1[4 * _m + 3]);             \
    }                                                                         \
    {                                                                         \
      u32x2 _r0 = plswap(_cp0[0], _cp0[2]);                                   \
      u32x2 _r1 = plswap(_cp0[1], _cp0[3]);                                   \
      union { u32x4 u; bf16x8 v; } _pu;                                       \
      _pu.u = (u32x4){_r0[0], _r1[0], _r0[1], _r1[1]};                        \
      oacc0 = mfma32(VV0, _pu.v, oacc0);                                      \
      oacc1 = mfma32(VV4, _pu.v, oacc1);                                      \
    }                                                                         \
    {                                                                         \
      u32x2 _r0 = plswap(_cp0[4], _cp0[6]);                                   \
      u32x2 _r1 = plswap(_cp0[5], _cp0[7]);                                   \
      union { u32x4 u; bf16x8 v; } _pu;                                       \
      _pu.u = (u32x4){_r0[0], _r1[0], _r0[1], _r1[1]};                        \
      oacc0 = mfma32(VV1, _pu.v, oacc0);                                      \
      oacc1 = mfma32(VV5, _pu.v, oacc1);                                      \
    }                                                                         \
    {                                                                         \
      u32x2 _r0 = plswap(_cp1[0], _cp1[2]);                                   \
      u32x2 _r1 = plswap(_cp1[1], _cp1[3]);                                   \
      union { u32x4 u; bf16x8 v; } _pu;                                       \
      _pu.u = (u32x4){_r0[0], _r1[0], _r0[1], _r1[1]};                        \
      oacc0 = mfma32(VV2, _pu.v, oacc0);                                      \
      oacc1 = mfma32(VV6, _pu.v, oacc1);                                      \
    }                                                                         \
    {                                                                         \
      u32x2 _r0 = plswap(_cp1[4], _cp1[6]);                                   \
      u32x2 _r1 = plswap(_cp1[5], _cp1[7]);                                   \
      union { u32x4 u; bf16x8 v; } _pu;                                       \
      _pu.u = (u32x4){_r0[0], _r1[0], _r0[1], _r1[1]};                        \
      oacc0 = mfma32(VV3, _pu.v, oacc0);                                      \
      oacc1 = mfma32(VV7, _pu.v, oacc1);                                      \
    }                                                                         \
  } while (0)

  bf16x8 kA0, kA1, kA2, kA3, kA4, kA5, kA6, kA7;
  bf16x8 kB0, kB1, kB2, kB3, kB4, kB5, kB6, kB7;
  bf16x8 VV0, VV1, VV2, VV3, VV4, VV5, VV6, VV7;
  f32x16 svA0, svA1, svB0, svB1;

  // Prologue: K(0) -> QK(0) into svA; K(1) into kB.
  LOADK8(kA0, kA1, kA2, kA3, kA4, kA5, kA6, kA7, 0);
  QK64(svA0, svA1, kA0, kA1, kA2, kA3, kA4, kA5, kA6, kA7);
  if (1 < NT) LOADK8(kB0, kB1, kB2, kB3, kB4, kB5, kB6, kB7, 1);

  int j = 0;
  #pragma unroll 1
  for (;;) {
    // phase A: tile j in svA; K(j+1) in kB; K(j+2) -> kA
    LOADV8(j);
    if (j + 1 < NT)
      QK64(svB0, svB1, kB0, kB1, kB2, kB3, kB4, kB5, kB6, kB7);
    if (j + 2 < NT)
      LOADK8(kA0, kA1, kA2, kA3, kA4, kA5, kA6, kA7, j + 2);
    SMPV(svA0, svA1, j);
    if (++j >= NT) break;

    // phase B: tile j in svB; K(j+1) in kA; K(j+2) -> kB
    LOADV8(j);
    if (j + 1 < NT)
      QK64(svA0, svA1, kA0, kA1, kA2, kA3, kA4, kA5, kA6, kA7);
    if (j + 2 < NT)
      LOADK8(kB0, kB1, kB2, kB3, kB4, kB5, kB6, kB7, j + 2);
    SMPV(svB0, svB1, j);
    if (++j >= NT) break;
  }
#undef SMPV
#undef QK64
#undef LOADV8
#undef LOADK8

  // ---- epilogue: O rows hd = (reg&3)+8*(reg>>2)+4hi, q col = l31 ----
  const float l_tot = l_run + __shfl_xor(l_run, 32);
  const float inv = 1.f / l_tot;
  const int b = bh >> 4, h = bh & 15;
  const int q_abs = q0w + l31;
  const size_t rowbase = ((size_t)(b * T + q_abs)) * 1024 + h * 64;
  #pragma unroll
  for (int rg = 0; rg < 4; ++rg) {
    bf16x4 o0, o1;
    #pragma unroll
    for (int r = 0; r < 4; ++r) {
      o0[r] = (__bf16)(oacc0[rg * 4 + r] * inv);
      o1[r] = (__bf16)(oacc1[rg * 4 + r] * inv);
    }
    *reinterpret_cast<bf16x4*>(&Ob[rowbase + rg * 8 + hi * 4])      = o0;
    *reinterpret_cast<bf16x4*>(&Ob[rowbase + 32 + rg * 8 + hi * 4]) = o1;
  }
}

// ---------------------------------------------------------------------------
extern "C" void kernel_launch(void* const* d_in, const int* in_sizes, int n_in,
                              void* d_out, int out_size, void* d_ws, size_t ws_size,
                              hipStream_t stream) {
  const float* x    = (const float*)d_in[0];
  const float* cosT = (const float*)d_in[1];
  const float* sinT = (const float*)d_in[2];
  // d_in[3] = mask (causal, analytic)
  const float* wq   = (const float*)d_in[4];
  const float* wk   = (const float*)d_in[5];
  const float* wv   = (const float*)d_in[6];
  const float* wo   = (const float*)d_in[7];
  float* out = (float*)d_out;

  __bf16* xb   = (__bf16*)d_ws;
  __bf16* wqb  = xb  + XSZ;
  __bf16* wkb  = wqb + WSZ;
  __bf16* wvb  = wkb + WSZ;
  __bf16* wob  = wvb + WSZ;
  __bf16* Qfb  = wob + WSZ;      // fragment-order Q (pre-scaled)
  __bf16* Kfb  = Qfb + XSZ;      // fragment-order K
  __bf16* Vfb  = Kfb + XSZ;      // fragment-order V
  __bf16* attb = Vfb + XSZ;      // [M][1024]

  cvt_all<<<(XSZ + 4 * WSZ) / 8 / 256, 256, 0, stream>>>(x, wq, wk, wv, wo, xb);

  gemm_mfma<1><<<dim3(24, 32), 256, 0, stream>>>(
      xb, wqb, wkb, wvb, cosT, sinT, Qfb, Kfb, Vfb);

  attn_v15<<<dim3(16, 32), 256, 0, stream>>>(Qfb, Kfb, Vfb, attb);

  gemm_mfma<0><<<dim3(8, 64), 256, 0, stream>>>(
      attb, wob, nullptr, nullptr, nullptr, nullptr, out, nullptr, nullptr);
}